// Round 9
// baseline (418.972 us; speedup 1.0000x reference)
//
#include <hip/hip_runtime.h>
#include <cstddef>

// LiteMLA: qkv GEMM (split-fp16 MFMA, 3-pass) -> dwconv5x5+groupmix ->
// linear attention (split stats/apply) -> proj GEMM (split-A fp16, 2-pass)+BN.
// B=4, C=512, H=W=64, N=4096, heads=128, 24 ch/head.
//
// Precision: split fp16 (hi+lo) GEMMs; absmax 0.0039 vs thr 0.013 (R4).
//
// Measured models (R8 counters):
//   qkv GEMM 89.6us @ MfmaUtil 38% = 863 TF = m97-structure plateau. Leave.
//   dwpw 90us = LDS-issue bound: 200 ds_read_b32/px x 5.8cyc -> 92us model.
//   R9: dwpw v4 = 2px/thread, 3x float2 (b64) window reads -> 60 LDS inst/px,
//   tile[8][12][68]=26.1KB (5 blk/CU), dwv[8][2] keeps VGPR ~45.
//   (R5: 45KB LDS -> 3 blk/CU, 113us. R6: VGPR 172 -> 2 blk/CU, 223us.
//    Lesson: occupancy >= 5 blk/CU is the constraint; cut LDS insts within it.)
// attn: (b,h)-only grids (512 blk) are latency-dead (R7, 138us); n-split
// stats (2048 blk) + apply (8192 blk) = proven R8.
//
// Workspace (peak 229 MiB):
//   qkv fp32     100663296 @ 0
//   y   fp32     100663296 @ 100663296
//   x_t_h fp16    16777216 @ 201326592  (dead after qkv GEMM)
//   x_t_l fp16    16777216 @ 218103808  (dead after qkv GEMM)
//   attout fp16   33554432 @ 201326592  (overlays x_t after it's dead)
//   w_qkv_h/l     1572864*2 @ 234881024
//   w_proj_h/l    1048576*2 @ 238026752
// vk partials (590 KB) live in d_out (proj GEMM fully overwrites d_out after).

#define NPIX 4096
#define TD3 1536

typedef _Float16 f16;
typedef __attribute__((ext_vector_type(8))) _Float16 v8h;
typedef __attribute__((ext_vector_type(4))) float v4f;
typedef unsigned short ushort_t;

#define GLL16(g, l) __builtin_amdgcn_global_load_lds(                         \
    (const __attribute__((address_space(1))) unsigned int*)(g),               \
    (__attribute__((address_space(3))) unsigned int*)(l), 16, 0, 0)

// ---------------------------------------------------------------------------
// Split fp16 MFMA GEMM (m97 structure). Ah/Al (M x K) row-major fp16,
// Bh (and Bl if SPLITB) (N x K) row-major fp16, C (M x N) fp32.
// 128x128 tile, BK=32, 256 threads = 4 waves, each wave 64x64 via 4x4 grid
// of 16x16x32 MFMAs. C = Ah*Bh + Al*Bh (+ Ah*Bl if SPLITB). BN epilogue opt.
// ---------------------------------------------------------------------------
template <int SPLITB, int BN>
__global__ __launch_bounds__(256) void gemm_f16(
    const f16* __restrict__ Ah, const f16* __restrict__ Al,
    const f16* __restrict__ Bh, const f16* __restrict__ Bl,
    float* __restrict__ C, int M, int N, int K,
    const float* __restrict__ bn_g, const float* __restrict__ bn_b,
    const float* __restrict__ bn_m, const float* __restrict__ bn_v)
{
    __shared__ f16 AsH[128 * 32];
    __shared__ f16 AsL[128 * 32];
    __shared__ f16 BsH[128 * 32];
    __shared__ f16 BsL[SPLITB ? 128 * 32 : 64];

    const int tid  = threadIdx.x;
    const int lane = tid & 63;
    const int w    = tid >> 6;
    const int wm   = w >> 1, wn = w & 1;
    const int mBase = blockIdx.y * 128, nBase = blockIdx.x * 128;
    Bh += (size_t)blockIdx.z * N * K;
    if (SPLITB) Bl += (size_t)blockIdx.z * N * K;
    C  += (size_t)blockIdx.z * M * N;

    const f16* gAh[2]; const f16* gAl[2]; const f16* gBh[2]; const f16* gBl[2];
    int ldsOff[2];
    #pragma unroll
    for (int p = 0; p < 2; ++p) {
        int off = (w * 2 + p) * 1024 + lane * 16;  // byte offset in tile
        int r  = off >> 6;                         // row (64 B = 32 f16)
        int ci = (off & 63) >> 1;                  // f16 col index
        gAh[p] = Ah + (size_t)(mBase + r) * K + ci;
        gAl[p] = Al + (size_t)(mBase + r) * K + ci;
        gBh[p] = Bh + (size_t)(nBase + r) * K + ci;
        if (SPLITB) gBl[p] = Bl + (size_t)(nBase + r) * K + ci;
        ldsOff[p] = (w * 2 + p) * 512;
    }

    v4f acc[4][4];
    #pragma unroll
    for (int i = 0; i < 4; ++i)
        #pragma unroll
        for (int j = 0; j < 4; ++j)
            acc[i][j] = (v4f){0.f, 0.f, 0.f, 0.f};

    const int kq = lane >> 4;
    const int rm = lane & 15;
    const int KT = K >> 5;
    for (int kt = 0; kt < KT; ++kt) {
        #pragma unroll
        for (int p = 0; p < 2; ++p) {
            GLL16(gAh[p] + kt * 32, &AsH[ldsOff[p]]);
            GLL16(gAl[p] + kt * 32, &AsL[ldsOff[p]]);
            GLL16(gBh[p] + kt * 32, &BsH[ldsOff[p]]);
            if (SPLITB) GLL16(gBl[p] + kt * 32, &BsL[ldsOff[p]]);
        }
        __syncthreads();

        v8h ah[4], al[4], bh[4], bl[4];
        #pragma unroll
        for (int i = 0; i < 4; ++i) {
            ah[i] = *(const v8h*)&AsH[(wm * 64 + i * 16 + rm) * 32 + kq * 8];
            al[i] = *(const v8h*)&AsL[(wm * 64 + i * 16 + rm) * 32 + kq * 8];
            bh[i] = *(const v8h*)&BsH[(wn * 64 + i * 16 + rm) * 32 + kq * 8];
            if (SPLITB)
                bl[i] = *(const v8h*)&BsL[(wn * 64 + i * 16 + rm) * 32 + kq * 8];
        }
        #pragma unroll
        for (int i = 0; i < 4; ++i)
            #pragma unroll
            for (int j = 0; j < 4; ++j) {
                acc[i][j] = __builtin_amdgcn_mfma_f32_16x16x32_f16(
                    ah[i], bh[j], acc[i][j], 0, 0, 0);
                acc[i][j] = __builtin_amdgcn_mfma_f32_16x16x32_f16(
                    al[i], bh[j], acc[i][j], 0, 0, 0);
                if (SPLITB)
                    acc[i][j] = __builtin_amdgcn_mfma_f32_16x16x32_f16(
                        ah[i], bl[j], acc[i][j], 0, 0, 0);
            }
        __syncthreads();
    }

    const int rq = lane >> 4, cn = lane & 15;
    #pragma unroll
    for (int i = 0; i < 4; ++i) {
        #pragma unroll
        for (int rg = 0; rg < 4; ++rg) {
            int row = mBase + wm * 64 + i * 16 + rq * 4 + rg;
            float sc = 1.f, sh = 0.f;
            if (BN) {
                sc = bn_g[row] * rsqrtf(bn_v[row] + 1e-5f);
                sh = bn_b[row] - bn_m[row] * sc;
            }
            #pragma unroll
            for (int j = 0; j < 4; ++j) {
                int col = nBase + wn * 64 + j * 16 + cn;
                float v = acc[i][j][rg];
                C[(size_t)row * N + col] = BN ? (v * sc + sh) : v;
            }
        }
    }
}

// ---------------------------------------------------------------------------
// fp32 -> (fp16 hi, fp16 lo) for BOTH weight matrices in one launch.
// ---------------------------------------------------------------------------
__global__ __launch_bounds__(256) void cvt_split2(
    const float* __restrict__ a, f16* __restrict__ ah, f16* __restrict__ al,
    int n4a,
    const float* __restrict__ bsrc, f16* __restrict__ bh, f16* __restrict__ bl,
    int n4b)
{
    int i = blockIdx.x * 256 + threadIdx.x;
    const float* s; f16 *dh, *dl; int idx;
    if (i < n4a) { s = a; dh = ah; dl = al; idx = i; }
    else {
        idx = i - n4a;
        if (idx >= n4b) return;
        s = bsrc; dh = bh; dl = bl;
    }
    float4 f = ((const float4*)s)[idx];
    f16 h[4], l[4];
    float ff[4] = {f.x, f.y, f.z, f.w};
    #pragma unroll
    for (int q = 0; q < 4; ++q) {
        h[q] = (f16)ff[q];
        l[q] = (f16)(ff[q] - (float)h[q]);
    }
    *(uint2*)&dh[(size_t)idx * 4] = *(uint2*)h;
    *(uint2*)&dl[(size_t)idx * 4] = *(uint2*)l;
}

// ---------------------------------------------------------------------------
// Transpose + split: x (b, c=512, n=4096) fp32 -> x_t_h/l (b, n, c) fp16.
// ---------------------------------------------------------------------------
__global__ __launch_bounds__(256) void transp_split(
    const float* __restrict__ src, f16* __restrict__ dh, f16* __restrict__ dl)
{
    __shared__ float t[64][65];
    const int tid = threadIdx.x;
    const int n0 = blockIdx.x * 64, c0 = blockIdx.y * 64, b = blockIdx.z;

    const int row = tid >> 2;
    const int nn  = (tid & 3) * 16;
    const float* sp = src + ((size_t)b * 512 + c0 + row) * NPIX + n0 + nn;
    #pragma unroll
    for (int q = 0; q < 4; ++q) {
        float4 f = *(const float4*)(sp + q * 4);
        t[row][nn + q * 4 + 0] = f.x;
        t[row][nn + q * 4 + 1] = f.y;
        t[row][nn + q * 4 + 2] = f.z;
        t[row][nn + q * 4 + 3] = f.w;
    }
    __syncthreads();

    const int nrow = tid >> 2;
    const int cc   = (tid & 3) * 16;
    f16 h[16], l[16];
    #pragma unroll
    for (int q = 0; q < 16; ++q) {
        float f = t[cc + q][nrow];
        h[q] = (f16)f;
        l[q] = (f16)(f - (float)h[q]);
    }
    size_t di = ((size_t)b * NPIX + n0 + nrow) * 512 + c0 + cc;
    *(uint4*)&dh[di] = *(uint4*)&h[0];
    *(uint4*)&dh[di + 8] = *(uint4*)&h[8];
    *(uint4*)&dl[di] = *(uint4*)&l[0];
    *(uint4*)&dl[di + 8] = *(uint4*)&l[8];
}

// ---------------------------------------------------------------------------
// Fused depthwise 5x5 conv (pad 2) + per-group 8x8 mix — v4.
// Block = (b, g, 8 output rows), 256 threads. Thread (r=tid>>5, wc=tid&31)
// computes a 1x2 px strip for all 8 ch: per (ch,tap-row) three 8B-aligned
// float2 LDS reads (window cols wc*2..wc*2+5) -> 60 LDS insts/px vs R4's 200.
// tile[8][12][68] = 26.1 KB -> 5 blocks/CU; dwv[8][2] keeps VGPR low.
// Staging: lane=col (coalesced 256B), wave-uniform row predicate, col halo
// constant-zero. No integer divides anywhere.
// ---------------------------------------------------------------------------
__global__ __launch_bounds__(256) void dwpw(
    const float* __restrict__ qkv, const float* __restrict__ w_dw,
    const float* __restrict__ w_pw, float* __restrict__ y)
{
    __shared__ float tile[8][12][68];   // 26112 B
    __shared__ float wd[8][25];
    __shared__ float wp[64];

    const int tid = threadIdx.x;
    const int g = blockIdx.y;
    const int b = blockIdx.z;
    const int h0 = blockIdx.x * 8;
    const size_t cbase = (size_t)b * TD3 + g * 8;

    if (tid < 200) wd[tid / 25][tid % 25] = w_dw[(g * 8 + tid / 25) * 25 + tid % 25];
    if (tid >= 192) wp[tid - 192] = w_pw[g * 64 + (tid - 192)];

    const int srow = tid >> 6;      // 0..3, wave-uniform
    const int scol = tid & 63;      // lane = col
    #pragma unroll
    for (int ch = 0; ch < 8; ++ch) {
        const float* gp = qkv + (cbase + ch) * NPIX;
        #pragma unroll
        for (int pass = 0; pass < 3; ++pass) {
            int row = pass * 4 + srow;          // 0..11
            int gh = h0 + row - 2;              // wave-uniform predicate
            float v = (gh >= 0 && gh < 64) ? gp[gh * 64 + scol] : 0.f;
            tile[ch][row][scol + 2] = v;
            if (scol < 2)   tile[ch][row][scol] = 0.f;      // cols 0,1
            if (scol >= 62) tile[ch][row][scol + 4] = 0.f;  // cols 66,67
        }
    }
    __syncthreads();

    const int r  = tid >> 5;        // 0..7 output row
    const int wc = tid & 31;        // output cols wc*2, wc*2+1
    float dwv[8][2];
    #pragma unroll
    for (int ch = 0; ch < 8; ++ch) {
        float s0 = 0.f, s1 = 0.f;
        #pragma unroll
        for (int di = 0; di < 5; ++di) {
            const float* rp = &tile[ch][r + di][wc * 2];   // 8B-aligned
            float2 w0 = *(const float2*)(rp);
            float2 w1 = *(const float2*)(rp + 2);
            float2 w2 = *(const float2*)(rp + 4);
            float win[6] = {w0.x, w0.y, w1.x, w1.y, w2.x, w2.y};
            #pragma unroll
            for (int dj = 0; dj < 5; ++dj) {
                float wgt = wd[ch][di * 5 + dj];
                s0 = fmaf(win[dj], wgt, s0);
                s1 = fmaf(win[dj + 1], wgt, s1);
            }
        }
        dwv[ch][0] = s0; dwv[ch][1] = s1;
    }
    #pragma unroll
    for (int o = 0; o < 8; ++o) {
        float2 s = {0.f, 0.f};
        #pragma unroll
        for (int i = 0; i < 8; ++i) {
            float wgt = wp[o * 8 + i];
            s.x = fmaf(dwv[i][0], wgt, s.x);
            s.y = fmaf(dwv[i][1], wgt, s.y);
        }
        *(float2*)&y[(cbase + o) * NPIX + (h0 + r) * 64 + wc * 2] = s;
    }
}

// ---------------------------------------------------------------------------
// Attention stats, n-split: block (p, h, b) reduces n in [p*1024,(p+1)*1024)
// to partial vk[9][8], written to vkp[((p*4+b)*128+h)*72 + i]. 2048 blocks.
// ---------------------------------------------------------------------------
__global__ __launch_bounds__(256) void attn_stats(
    const float* __restrict__ qkv, const float* __restrict__ yy,
    float* __restrict__ vkp)
{
    const int p = blockIdx.x;
    const int h = blockIdx.y;
    const int b = blockIdx.z;
    const float* src = (h < 64)
        ? qkv + ((size_t)b * TD3 + h * 24) * NPIX
        : yy  + ((size_t)b * TD3 + (h - 64) * 24) * NPIX;

    float acc[9][8];
    #pragma unroll
    for (int d = 0; d < 9; ++d)
        #pragma unroll
        for (int e = 0; e < 8; ++e) acc[d][e] = 0.f;

    const int n0 = p * 1024;
    for (int n = n0 + threadIdx.x; n < n0 + 1024; n += 256) {
        float kr[8], vv[8];
        #pragma unroll
        for (int e = 0; e < 8; ++e) kr[e] = fmaxf(src[(8 + e) * NPIX + n], 0.f);
        #pragma unroll
        for (int d = 0; d < 8; ++d) vv[d] = src[(16 + d) * NPIX + n];
        #pragma unroll
        for (int d = 0; d < 8; ++d)
            #pragma unroll
            for (int e = 0; e < 8; ++e) acc[d][e] = fmaf(vv[d], kr[e], acc[d][e]);
        #pragma unroll
        for (int e = 0; e < 8; ++e) acc[8][e] += kr[e];
    }

    __shared__ float part[4][72];
    const int lane = threadIdx.x & 63, wave = threadIdx.x >> 6;
    #pragma unroll
    for (int i = 0; i < 72; ++i) {
        float v = acc[i / 8][i % 8];
        #pragma unroll
        for (int off = 32; off; off >>= 1) v += __shfl_down(v, off, 64);
        if (lane == 0) part[wave][i] = v;
    }
    __syncthreads();
    if (threadIdx.x < 72) {
        float v = part[0][threadIdx.x] + part[1][threadIdx.x] +
                  part[2][threadIdx.x] + part[3][threadIdx.x];
        vkp[(((size_t)p * 4 + b) * 128 + h) * 72 + threadIdx.x] = v;
    }
}

// ---------------------------------------------------------------------------
// Attention apply: sums the 4 vk partials, out[d,n] written transposed fp16
// into attout (b,n,c). Grid (16,128,4) = 8192 blocks.
// ---------------------------------------------------------------------------
__global__ __launch_bounds__(256) void attn_apply_t(
    const float* __restrict__ qkv, const float* __restrict__ yy,
    const float* __restrict__ vkp, f16* __restrict__ attout)
{
    const int h = blockIdx.y;
    const int b = blockIdx.z;
    const int n = blockIdx.x * 256 + threadIdx.x;

    __shared__ float vk[72];
    if (threadIdx.x < 72) {
        float s = 0.f;
        #pragma unroll
        for (int p = 0; p < 4; ++p)
            s += vkp[(((size_t)p * 4 + b) * 128 + h) * 72 + threadIdx.x];
        vk[threadIdx.x] = s;
    }
    __syncthreads();

    const float* src = (h < 64)
        ? qkv + ((size_t)b * TD3 + h * 24) * NPIX
        : yy  + ((size_t)b * TD3 + (h - 64) * 24) * NPIX;

    float qr[8];
    #pragma unroll
    for (int e = 0; e < 8; ++e) qr[e] = fmaxf(src[e * NPIX + n], 0.f);

    float den = 0.f;
    #pragma unroll
    for (int e = 0; e < 8; ++e) den = fmaf(vk[64 + e], qr[e], den);
    float inv = 1.f / (den + 1e-15f);

    f16 o[8];
    #pragma unroll
    for (int d = 0; d < 8; ++d) {
        float num = 0.f;
        #pragma unroll
        for (int e = 0; e < 8; ++e) num = fmaf(vk[d * 8 + e], qr[e], num);
        o[d] = (f16)(num * inv);
    }
    *(uint4*)&attout[((size_t)b * NPIX + n) * 1024 + h * 8] = *(uint4*)o;
}

// ---------------------------------------------------------------------------
extern "C" void kernel_launch(void* const* d_in, const int* in_sizes, int n_in,
                              void* d_out, int out_size, void* d_ws, size_t ws_size,
                              hipStream_t stream)
{
    (void)in_sizes; (void)n_in; (void)out_size; (void)ws_size;
    const float* x      = (const float*)d_in[0];
    const float* w_qkv  = (const float*)d_in[1];
    const float* w_dw   = (const float*)d_in[2];
    const float* w_pw   = (const float*)d_in[3];
    const float* w_proj = (const float*)d_in[4];
    const float* bn_g   = (const float*)d_in[5];
    const float* bn_b   = (const float*)d_in[6];
    const float* bn_m   = (const float*)d_in[7];
    const float* bn_v   = (const float*)d_in[8];
    float* out = (float*)d_out;

    char* ws = (char*)d_ws;
    float* qkv     = (float*)(ws);
    float* y       = (float*)(ws + 100663296);
    f16*   x_t_h   = (f16*)(ws + 201326592);    // dead after qkv GEMM
    f16*   x_t_l   = (f16*)(ws + 218103808);    // dead after qkv GEMM
    f16*   attout  = (f16*)(ws + 201326592);    // overlays x_t_h/l
    f16*   w_qkv_h = (f16*)(ws + 234881024);
    f16*   w_qkv_l = (f16*)(ws + 236453888);
    f16*   w_proj_h= (f16*)(ws + 238026752);
    f16*   w_proj_l= (f16*)(ws + 239075328);
    float* vkp     = out;                        // 590 KB scratch in d_out;
                                                 // proj GEMM overwrites after

    // 0. split both weight matrices to fp16 hi/lo (one launch)
    cvt_split2<<<1280, 256, 0, stream>>>(w_qkv, w_qkv_h, w_qkv_l, 196608,
                                         w_proj, w_proj_h, w_proj_l, 131072);
    // 1. x (b,c,n) -> x_t (b,n,c) fp16 hi/lo
    transp_split<<<dim3(64, 8, 4), 256, 0, stream>>>(x, x_t_h, x_t_l);
    // 2. qkv = w_qkv @ x  (M=1536,N=4096,K=512, batch 4), 3-pass split
    gemm_f16<1, 0><<<dim3(32, 12, 4), 256, 0, stream>>>(
        w_qkv_h, w_qkv_l, x_t_h, x_t_l, qkv, 1536, 4096, 512,
        nullptr, nullptr, nullptr, nullptr);
    // 3. y = groupmix(dwconv5x5(qkv))
    dwpw<<<dim3(8, 192, 4), 256, 0, stream>>>(qkv, w_dw, w_pw, y);
    // 4. attention stats (4-way n-split partials) -> vkp (in d_out)
    attn_stats<<<dim3(4, 128, 4), 256, 0, stream>>>(qkv, y, vkp);
    // 5. attention apply -> attout (b,n,c) fp16
    attn_apply_t<<<dim3(16, 128, 4), 256, 0, stream>>>(qkv, y, vkp, attout);
    // 6. out = BN(w_proj @ attout)  (M=512,N=4096,K=1024, batch 4), 2-pass
    gemm_f16<0, 1><<<dim3(32, 4, 4), 256, 0, stream>>>(
        w_proj_h, w_proj_l, attout, nullptr, out, 512, 4096, 1024,
        bn_g, bn_b, bn_m, bn_v);
}